// Round 13
// baseline (194.204 us; speedup 1.0000x reference)
//
#include <hip/hip_runtime.h>
#include <math.h>

#define N_NODES 50000
#define HID 128
#define N_EDGES 600000

typedef __attribute__((ext_vector_type(8))) short s16x8;
typedef __attribute__((ext_vector_type(4))) float f32x4;
typedef __attribute__((ext_vector_type(4))) uint u32x4;

// RNE float -> bf16 bits (finite inputs only)
__device__ __forceinline__ ushort f2b(float f) {
    uint x = __builtin_bit_cast(uint, f);
    uint r = (x + 0x7FFFu + ((x >> 16) & 1u)) >> 16;
    return (ushort)r;
}
__device__ __forceinline__ float b2f(ushort u) {
    return __builtin_bit_cast(float, (uint)u << 16);
}
__device__ __forceinline__ float gelu_exact(float y) {
    return 0.5f * y * (1.0f + erff(y * 0.70710678118654752f));
}

// ------------------------------------------- prep: wfrag swizzle + cnt zero -
// wfrag word ((ct*4+ks)*64 + lane)*4 + w holds bf16 pair (W[k0][n], W[k0+1][n]),
// k0 = ks*32 + (lane>>4)*8 + 2w, n = ct*16 + (lane&15). Two matrices.
// Tail blocks zero the cnt array (grid-strided into one launch).
__global__ __launch_bounds__(256) void prep_kernel(
        const float* __restrict__ W1, const float* __restrict__ W2,
        uint* __restrict__ wfrag, u32x4* __restrict__ cnt4, int n4) {
    int id = blockIdx.x * 256 + threadIdx.x;
    if (id < 16384) {
        const float* W = (id < 8192) ? W1 : W2;
        int q = id & 8191;
        int l16 = q & 15;
        int w   = (q >> 4) & 3;
        int kg  = (q >> 6) & 3;
        int f   = q >> 8;                         // ct*4+ks, 0..31
        int ct = f >> 2, ks = f & 3;
        int n  = ct * 16 + l16;
        int k0 = ks * 32 + kg * 8 + 2 * w;
        uint lo = f2b(W[(size_t)k0 * HID + n]);
        uint hi = f2b(W[(size_t)(k0 + 1) * HID + n]);
        size_t widx = ((size_t)(id >> 13) * 8192) +
                      ((size_t)f * 64 + kg * 16 + l16) * 4 + w;
        wfrag[widx] = lo | (hi << 16);
    } else {
        int z = id - 16384;
        if (z < n4) cnt4[z] = (u32x4)(0u);
    }
}

// ---------------------------------------------------------------- degree ----
__global__ void count_deg_kernel(const int4* __restrict__ dst4, int* cnt, int e4) {
    int i = blockIdx.x * blockDim.x + threadIdx.x;
    if (i < e4) {
        int4 d = dst4[i];
        atomicAdd(&cnt[d.x], 1); atomicAdd(&cnt[d.y], 1);
        atomicAdd(&cnt[d.z], 1); atomicAdd(&cnt[d.w], 1);
    }
}

// fused: dinv[i] = rsqrt(cnt[i]+1)  AND  bsum[blk] = sum(cnt) for the scan
__global__ __launch_bounds__(256) void reduce_dinv_kernel(
        const int* __restrict__ cnt, float* __restrict__ dinv,
        int* __restrict__ bsum, int n) {
    int i = blockIdx.x * 256 + threadIdx.x;
    int v = (i < n) ? cnt[i] : 0;
    if (i < n) dinv[i] = rsqrtf((float)(v + 1));   // +1 self-loop
#pragma unroll
    for (int off = 32; off >= 1; off >>= 1) v += __shfl_xor(v, off);
    __shared__ int ws[4];
    if ((threadIdx.x & 63) == 0) ws[threadIdx.x >> 6] = v;
    __syncthreads();
    if (threadIdx.x == 0) bsum[blockIdx.x] = ws[0] + ws[1] + ws[2] + ws[3];
}

__global__ __launch_bounds__(256) void scan_bsum_kernel(int* bsum, int nb) {
    int t = threadIdx.x;
    int v = (t < nb) ? bsum[t] : 0;
    int x = v;
#pragma unroll
    for (int off = 1; off < 64; off <<= 1) {
        int y = __shfl_up(x, off);
        if ((t & 63) >= off) x += y;
    }
    __shared__ int wtot[4];
    if ((t & 63) == 63) wtot[t >> 6] = x;
    __syncthreads();
    int add = 0;
    for (int w = 0; w < (t >> 6); ++w) add += wtot[w];
    if (t < nb) bsum[t] = x - v + add;   // exclusive
}

__global__ __launch_bounds__(256) void scan_block_kernel(
        const int* __restrict__ cnt, const int* __restrict__ bOff,
        int* __restrict__ offs, int n) {
    int i = blockIdx.x * 256 + threadIdx.x;
    int v = (i < n) ? cnt[i] : 0;
    int x = v;
#pragma unroll
    for (int off = 1; off < 64; off <<= 1) {
        int y = __shfl_up(x, off);
        if ((threadIdx.x & 63) >= off) x += y;
    }
    __shared__ int wtot[4];
    if ((threadIdx.x & 63) == 63) wtot[threadIdx.x >> 6] = x;
    __syncthreads();
    int add = bOff[blockIdx.x];
    for (int w = 0; w < (threadIdx.x >> 6); ++w) add += wtot[w];
    if (i < n) offs[i] = x - v + add;    // exclusive scan = segment start
}

__global__ void fill_csr_kernel(const int4* __restrict__ src4,
                                const int4* __restrict__ dst4,
                                int* __restrict__ offs,
                                int* __restrict__ srcPerm, int e4) {
    int i = blockIdx.x * blockDim.x + threadIdx.x;
    if (i < e4) {
        int4 s = src4[i];
        int4 d = dst4[i];
        srcPerm[atomicAdd(&offs[d.x], 1)] = s.x;
        srcPerm[atomicAdd(&offs[d.y], 1)] = s.y;
        srcPerm[atomicAdd(&offs[d.z], 1)] = s.z;
        srcPerm[atomicAdd(&offs[d.w], 1)] = s.w;
    }
}

// ------------------------------------------------------------ MFMA GEMM -----
// H = dinv[r] * (A[r][:] @ W),  W pre-swizzled in fragment order.
// SLAB layout (u32 words): slab sl, row, word w (0..15) = bf16 pair of
// cols (sl*32 + w, sl*32 + 16 + w). GEMM lane packs acc[2sl],acc[2sl+1]
// into one u32 -> 16 coalesced 4 B stores (was 32 scattered 2 B stores).
template<bool LNG>
__global__ __launch_bounds__(256) void gemm_mfma_kernel(
        const float* __restrict__ Ap, const uint* __restrict__ wfrag,
        const float* __restrict__ dinv, const float* __restrict__ g,
        const float* __restrict__ be, uint* __restrict__ H, int M) {
    __shared__ u32x4 Wl[2048];                    // 32 KB, fragment order
    const u32x4* wf4 = (const u32x4*)wfrag;
#pragma unroll
    for (int i = 0; i < 8; ++i)
        Wl[threadIdx.x + i * 256] = wf4[threadIdx.x + i * 256];
    __syncthreads();

    const int l  = threadIdx.x & 63;
    const int wv = threadIdx.x >> 6;
    const int r0 = blockIdx.x * 64 + wv * 16;
    if (r0 >= M) return;              // M % 16 == 0 -> whole waves only
    const int arow = r0 + (l & 15);
    const int kg = l >> 4;            // 0..3

    s16x8 afr[4];
    if (LNG) {
        const float* A = Ap + (long)arow * HID;
        float v[4][8];
        float s = 0.f, s2 = 0.f;
#pragma unroll
        for (int ks = 0; ks < 4; ++ks) {
            int k0 = ks * 32 + kg * 8;
            f32x4 a0 = __builtin_nontemporal_load((const f32x4*)(A + k0));
            f32x4 a1 = __builtin_nontemporal_load((const f32x4*)(A + k0 + 4));
            v[ks][0] = a0.x; v[ks][1] = a0.y; v[ks][2] = a0.z; v[ks][3] = a0.w;
            v[ks][4] = a1.x; v[ks][5] = a1.y; v[ks][6] = a1.z; v[ks][7] = a1.w;
#pragma unroll
            for (int j = 0; j < 8; ++j) { s += v[ks][j]; s2 += v[ks][j] * v[ks][j]; }
        }
        s  += __shfl_xor(s, 16);  s  += __shfl_xor(s, 32);
        s2 += __shfl_xor(s2, 16); s2 += __shfl_xor(s2, 32);
        float mu   = s * (1.0f / 128.0f);
        float var  = s2 * (1.0f / 128.0f) - mu * mu;
        float rstd = rsqrtf(var + 1e-5f);
#pragma unroll
        for (int ks = 0; ks < 4; ++ks) {
            int k0 = ks * 32 + kg * 8;
            s16x8 o;
#pragma unroll
            for (int j = 0; j < 8; ++j) {
                float y = (v[ks][j] - mu) * rstd * g[k0 + j] + be[k0 + j];
                o[j] = (short)f2b(gelu_exact(y));
            }
            afr[ks] = o;
        }
    } else {
        const float* A = Ap + (long)arow * HID;
#pragma unroll
        for (int ks = 0; ks < 4; ++ks) {
            int k0 = ks * 32 + kg * 8;
            f32x4 a0 = __builtin_nontemporal_load((const f32x4*)(A + k0));
            f32x4 a1 = __builtin_nontemporal_load((const f32x4*)(A + k0 + 4));
            s16x8 v;
            v[0] = (short)f2b(a0.x); v[1] = (short)f2b(a0.y);
            v[2] = (short)f2b(a0.z); v[3] = (short)f2b(a0.w);
            v[4] = (short)f2b(a1.x); v[5] = (short)f2b(a1.y);
            v[6] = (short)f2b(a1.z); v[7] = (short)f2b(a1.w);
            afr[ks] = v;
        }
    }

    float drv[4];
#pragma unroll
    for (int q = 0; q < 4; ++q) drv[q] = dinv[r0 + kg * 4 + q];

    f32x4 acc[8];
#pragma unroll
    for (int ct = 0; ct < 8; ++ct) acc[ct] = (f32x4)(0.f);

    const ushort* Wls = (const ushort*)Wl;
#pragma unroll
    for (int ct = 0; ct < 8; ++ct) {
#pragma unroll
        for (int ks = 0; ks < 4; ++ks) {
            // lane-linear: frag f = ct*4+ks, byte addr = (f*64 + l)*16
            s16x8 bfr = *(const s16x8*)(Wls + ((ct * 4 + ks) * 64 + l) * 8);
            acc[ct] = __builtin_amdgcn_mfma_f32_16x16x32_bf16(
                          afr[ks], bfr, acc[ct], 0, 0, 0);
        }
    }

    // packed slab store: word w=l16 of (sl,row) = (col sl*32+l16, col +16)
#pragma unroll
    for (int sl = 0; sl < 4; ++sl) {
        uint* slab = H + (size_t)sl * N_NODES * 16 + (l & 15);
#pragma unroll
        for (int q = 0; q < 4; ++q) {
            int row = r0 + kg * 4 + q;
            uint wlo = f2b(acc[2 * sl][q] * drv[q]);
            uint whi = f2b(acc[2 * sl + 1][q] * drv[q]);
            slab[(size_t)row * 16] = wlo | (whi << 16);
        }
    }
}

// --------------------------------------------------- column-sliced gather ---
// slice = blockIdx & 3 (slab = 3.2 MB, L2-resident per XCD). 16-lane group
// per node; lane l16 owns cols (sl*32+l16, sl*32+16+l16) as one u32 word.
// 16 indices fetched lane-parallel (64 B NT load), double-buffered;
// 16 independent 64 B row gathers into a register buffer (deep MLP).
__global__ __launch_bounds__(256) void agg_slice_kernel(
        const uint* __restrict__ hs2, const float* __restrict__ dinv,
        const int* __restrict__ offsEnd, const int* __restrict__ srcPerm,
        const float* __restrict__ b, float* __restrict__ t, int n) {
    const int sl    = blockIdx.x & 3;
    const int chunk = blockIdx.x >> 2;
    const int l16   = threadIdx.x & 15;
    const int grp   = threadIdx.x >> 4;          // 0..15 in block
    const int gw16  = (threadIdx.x & 63) & 48;   // group base lane in wave
    const int d     = chunk * 16 + grp;
    if (d >= n) return;

    const uint* hcol = hs2 + (size_t)sl * N_NODES * 16 + l16;  // slab column
    uint u = hcol[(size_t)d * 16];               // self-loop (pre-scaled)
    float acc0 = b2f((ushort)u);
    float acc1 = b2f((ushort)(u >> 16));

    const int beg = (d == 0) ? 0 : offsEnd[d - 1];
    const int end = offsEnd[d];

    int idx = (beg + l16 < end)
            ? __builtin_nontemporal_load(srcPerm + beg + l16) : 0;

    for (int base = beg; base < end; base += 16) {
        int m = end - base; if (m > 16) m = 16;
        int nbase = base + 16;
        int nidx = (nbase + l16 < end)
                 ? __builtin_nontemporal_load(srcPerm + nbase + l16) : 0;

        uint uu[16];
#pragma unroll
        for (int j = 0; j < 16; ++j) {
            int s = __shfl(idx, gw16 + j);       // 0 for j >= m (lane loaded 0)
            uu[j] = hcol[(size_t)s * 16];
        }
#pragma unroll
        for (int j = 0; j < 16; ++j) {
            uint val = (j < m) ? uu[j] : 0u;
            acc0 += b2f((ushort)val);
            acc1 += b2f((ushort)(val >> 16));
        }
        idx = nidx;
    }

    float dd = dinv[d];
    int col = sl * 32 + l16;
    float bx = b[col], by = b[col + 16];
    __builtin_nontemporal_store(acc0 * dd + bx, &t[(size_t)d * HID + col]);
    __builtin_nontemporal_store(acc1 * dd + by, &t[(size_t)d * HID + col + 16]);
}

// ----------------------------------------------------- LN + GELU (final) ----
__global__ __launch_bounds__(256) void ln_gelu2_kernel(
        const float* __restrict__ t, const float* __restrict__ g,
        const float* __restrict__ be, float* __restrict__ outf, int n) {
    int d = (int)((blockIdx.x * (long)blockDim.x + threadIdx.x) >> 6);
    int l = threadIdx.x & 63;
    if (d >= n) return;
    float v0 = __builtin_nontemporal_load(&t[(size_t)d * HID + 2 * l]);
    float v1 = __builtin_nontemporal_load(&t[(size_t)d * HID + 2 * l + 1]);

    float s  = v0 + v1;
    float s2 = v0 * v0 + v1 * v1;
#pragma unroll
    for (int off = 32; off >= 1; off >>= 1) {
        s  += __shfl_xor(s,  off);
        s2 += __shfl_xor(s2, off);
    }
    float mu   = s  * (1.0f / 128.0f);
    float var  = s2 * (1.0f / 128.0f) - mu * mu;
    float rstd = rsqrtf(var + 1e-5f);
    float2 gg = *(const float2*)&g[2 * l];
    float2 ee = *(const float2*)&be[2 * l];
    float o0 = gelu_exact((v0 - mu) * rstd * gg.x + ee.x);
    float o1 = gelu_exact((v1 - mu) * rstd * gg.y + ee.y);
    __builtin_nontemporal_store(o0, &outf[(size_t)d * HID + 2 * l]);
    __builtin_nontemporal_store(o1, &outf[(size_t)d * HID + 2 * l + 1]);
}

// ---------------------------------------------------------------- launch ----
extern "C" void kernel_launch(void* const* d_in, const int* in_sizes, int n_in,
                              void* d_out, int out_size, void* d_ws, size_t ws_size,
                              hipStream_t stream) {
    const float* x   = (const float*)d_in[0];
    const int*   ei  = (const int*)d_in[1];   // [2, E] int32
    const float* W1  = (const float*)d_in[2];
    const float* b1  = (const float*)d_in[3];
    const float* W2  = (const float*)d_in[4];
    const float* b2  = (const float*)d_in[5];
    const float* g1  = (const float*)d_in[6];
    const float* be1 = (const float*)d_in[7];
    const float* g2  = (const float*)d_in[8];
    const float* be2 = (const float*)d_in[9];
    float* out = (float*)d_out;

    const int* src = ei;
    const int* dst = ei + N_EDGES;

    // ws: hs slab bf16 [4][N][32] | t fp32 [N][128] | srcPerm [E]
    //     | dinv [N] | offs [N] | cnt [N+pad16] | bsum [256] | wfrag [2][8192]
    ushort* hs      = (ushort*)d_ws;
    float*  t       = (float*)(hs + (size_t)N_NODES * HID);
    int*    srcPerm = (int*)(t + (size_t)N_NODES * HID);
    float*  dinv    = (float*)(srcPerm + N_EDGES);
    int*    offs    = (int*)(dinv + N_NODES);
    int*    cnt     = offs + N_NODES;
    int*    bsum    = cnt + 50016;               // cnt padded to /16
    uint*   wfrag   = (uint*)(bsum + 256);

    const int B = 256;
    const int nodeB = (N_NODES + B - 1) / B;            // 196
    const int e4    = N_EDGES / 4;                      // 150000 (exact)
    const int edge4B = (e4 + B - 1) / B;
    const int gemm_blocks    = (N_NODES + 63) / 64;     // 782
    const int slice_blocks   = ((N_NODES + 15) / 16) * 4;  // 12500
    const int rowwave_blocks = (N_NODES + 3) / 4;       // 12500
    const int zero4 = 50016 / 4;                        // u32x4 count
    const int prepB = (16384 + zero4 + B - 1) / B;      // 113

    // prep (wfrag swizzle + cnt zero) + degree/CSR build
    prep_kernel<<<prepB, B, 0, stream>>>(W1, W2, wfrag, (u32x4*)cnt, zero4);
    count_deg_kernel<<<edge4B, B, 0, stream>>>((const int4*)dst, cnt, e4);
    reduce_dinv_kernel<<<nodeB, B, 0, stream>>>(cnt, dinv, bsum, N_NODES);
    scan_bsum_kernel<<<1, B, 0, stream>>>(bsum, nodeB);
    scan_block_kernel<<<nodeB, B, 0, stream>>>(cnt, bsum, offs, N_NODES);
    fill_csr_kernel<<<edge4B, B, 0, stream>>>((const int4*)src, (const int4*)dst,
                                              offs, srcPerm, e4);
    // post-fill: offs[d] == end of segment d

    // ---- layer 1 ----
    gemm_mfma_kernel<false><<<gemm_blocks, B, 0, stream>>>(
        x, wfrag, dinv, nullptr, nullptr, (uint*)hs, N_NODES);
    agg_slice_kernel<<<slice_blocks, B, 0, stream>>>(
        (const uint*)hs, dinv, offs, srcPerm, b1, t, N_NODES);

    // ---- layer 2 (LN1+GELU1 fused into GEMM2 A-load) ----
    gemm_mfma_kernel<true><<<gemm_blocks, B, 0, stream>>>(
        t, wfrag + 8192, dinv, g1, be1, (uint*)hs, N_NODES);
    agg_slice_kernel<<<slice_blocks, B, 0, stream>>>(
        (const uint*)hs, dinv, offs, srcPerm, b2, t, N_NODES);
    ln_gelu2_kernel<<<rowwave_blocks, B, 0, stream>>>(
        t, g2, be2, out, N_NODES);
}

// Round 14
// 180.756 us; speedup vs baseline: 1.0744x; 1.0744x over previous
//
#include <hip/hip_runtime.h>
#include <math.h>

#define N_NODES 50000
#define HID 128
#define N_EDGES 600000

typedef __attribute__((ext_vector_type(8))) short s16x8;
typedef __attribute__((ext_vector_type(4))) float f32x4;
typedef __attribute__((ext_vector_type(2))) float f32x2;
typedef __attribute__((ext_vector_type(4))) uint u32x4;

// RNE float -> bf16 bits (finite inputs only)
__device__ __forceinline__ ushort f2b(float f) {
    uint x = __builtin_bit_cast(uint, f);
    uint r = (x + 0x7FFFu + ((x >> 16) & 1u)) >> 16;
    return (ushort)r;
}
__device__ __forceinline__ float b2f(ushort u) {
    return __builtin_bit_cast(float, (uint)u << 16);
}
__device__ __forceinline__ float gelu_exact(float y) {
    return 0.5f * y * (1.0f + erff(y * 0.70710678118654752f));
}

// ------------------------------------------- prep: wfrag swizzle + cnt zero -
__global__ __launch_bounds__(256) void prep_kernel(
        const float* __restrict__ W1, const float* __restrict__ W2,
        uint* __restrict__ wfrag, u32x4* __restrict__ cnt4, int n4) {
    int id = blockIdx.x * 256 + threadIdx.x;
    if (id < 16384) {
        const float* W = (id < 8192) ? W1 : W2;
        int q = id & 8191;
        int l16 = q & 15;
        int w   = (q >> 4) & 3;
        int kg  = (q >> 6) & 3;
        int f   = q >> 8;                         // ct*4+ks, 0..31
        int ct = f >> 2, ks = f & 3;
        int n  = ct * 16 + l16;
        int k0 = ks * 32 + kg * 8 + 2 * w;
        uint lo = f2b(W[(size_t)k0 * HID + n]);
        uint hi = f2b(W[(size_t)(k0 + 1) * HID + n]);
        size_t widx = ((size_t)(id >> 13) * 8192) +
                      ((size_t)f * 64 + kg * 16 + l16) * 4 + w;
        wfrag[widx] = lo | (hi << 16);
    } else {
        int z = id - 16384;
        if (z < n4) cnt4[z] = (u32x4)(0u);
    }
}

// ---------------------------------------------------------------- degree ----
__global__ void count_deg_kernel(const int4* __restrict__ dst4, int* cnt, int e4) {
    int i = blockIdx.x * blockDim.x + threadIdx.x;
    if (i < e4) {
        int4 d = dst4[i];
        atomicAdd(&cnt[d.x], 1); atomicAdd(&cnt[d.y], 1);
        atomicAdd(&cnt[d.z], 1); atomicAdd(&cnt[d.w], 1);
    }
}

// fused: dinv[i] = rsqrt(cnt[i]+1)  AND  bsum[blk] = sum(cnt)
__global__ __launch_bounds__(256) void reduce_dinv_kernel(
        const int* __restrict__ cnt, float* __restrict__ dinv,
        int* __restrict__ bsum, int n) {
    int i = blockIdx.x * 256 + threadIdx.x;
    int v = (i < n) ? cnt[i] : 0;
    if (i < n) dinv[i] = rsqrtf((float)(v + 1));   // +1 self-loop
#pragma unroll
    for (int off = 32; off >= 1; off >>= 1) v += __shfl_xor(v, off);
    __shared__ int ws[4];
    if ((threadIdx.x & 63) == 0) ws[threadIdx.x >> 6] = v;
    __syncthreads();
    if (threadIdx.x == 0) bsum[blockIdx.x] = ws[0] + ws[1] + ws[2] + ws[3];
}

__global__ __launch_bounds__(256) void scan_bsum_kernel(int* bsum, int nb) {
    int t = threadIdx.x;
    int v = (t < nb) ? bsum[t] : 0;
    int x = v;
#pragma unroll
    for (int off = 1; off < 64; off <<= 1) {
        int y = __shfl_up(x, off);
        if ((t & 63) >= off) x += y;
    }
    __shared__ int wtot[4];
    if ((t & 63) == 63) wtot[t >> 6] = x;
    __syncthreads();
    int add = 0;
    for (int w = 0; w < (t >> 6); ++w) add += wtot[w];
    if (t < nb) bsum[t] = x - v + add;   // exclusive
}

__global__ __launch_bounds__(256) void scan_block_kernel(
        const int* __restrict__ cnt, const int* __restrict__ bOff,
        int* __restrict__ offs, int n) {
    int i = blockIdx.x * 256 + threadIdx.x;
    int v = (i < n) ? cnt[i] : 0;
    int x = v;
#pragma unroll
    for (int off = 1; off < 64; off <<= 1) {
        int y = __shfl_up(x, off);
        if ((threadIdx.x & 63) >= off) x += y;
    }
    __shared__ int wtot[4];
    if ((threadIdx.x & 63) == 63) wtot[threadIdx.x >> 6] = x;
    __syncthreads();
    int add = bOff[blockIdx.x];
    for (int w = 0; w < (threadIdx.x >> 6); ++w) add += wtot[w];
    if (i < n) offs[i] = x - v + add;    // exclusive scan = segment start
}

__global__ void fill_csr_kernel(const int4* __restrict__ src4,
                                const int4* __restrict__ dst4,
                                int* __restrict__ offs,
                                int* __restrict__ srcPerm, int e4) {
    int i = blockIdx.x * blockDim.x + threadIdx.x;
    if (i < e4) {
        int4 s = src4[i];
        int4 d = dst4[i];
        srcPerm[atomicAdd(&offs[d.x], 1)] = s.x;
        srcPerm[atomicAdd(&offs[d.y], 1)] = s.y;
        srcPerm[atomicAdd(&offs[d.z], 1)] = s.z;
        srcPerm[atomicAdd(&offs[d.w], 1)] = s.w;
    }
}

// ------------------------------------------------------------ MFMA GEMM -----
// H = dinv[r] * (A[r][:] @ W),  W pre-swizzled in fragment order.
// A is fp32 rows (layer 1, x) or bf16 rows (layer 2, z1) per AB16.
// SLAB layout (u32 words): slab sl, row, word w (0..15) = bf16 pair of
// cols (sl*32 + w, sl*32 + 16 + w). 16 coalesced 4 B stores per lane.
template<bool AB16>
__global__ __launch_bounds__(256) void gemm_mfma_kernel(
        const void* __restrict__ Ap, const uint* __restrict__ wfrag,
        const float* __restrict__ dinv, uint* __restrict__ H, int M) {
    __shared__ u32x4 Wl[2048];                    // 32 KB, fragment order
    const u32x4* wf4 = (const u32x4*)wfrag;
#pragma unroll
    for (int i = 0; i < 8; ++i)
        Wl[threadIdx.x + i * 256] = wf4[threadIdx.x + i * 256];
    __syncthreads();

    const int l  = threadIdx.x & 63;
    const int wv = threadIdx.x >> 6;
    const int r0 = blockIdx.x * 64 + wv * 16;
    if (r0 >= M) return;              // M % 16 == 0 -> whole waves only
    const int arow = r0 + (l & 15);
    const int kg = l >> 4;            // 0..3

    s16x8 afr[4];
    if (AB16) {
        const ushort* A = (const ushort*)Ap + (size_t)arow * HID;
#pragma unroll
        for (int ks = 0; ks < 4; ++ks)
            afr[ks] = __builtin_nontemporal_load(
                          (const s16x8*)(A + ks * 32 + kg * 8));
    } else {
        const float* A = (const float*)Ap + (size_t)arow * HID;
#pragma unroll
        for (int ks = 0; ks < 4; ++ks) {
            int k0 = ks * 32 + kg * 8;
            f32x4 a0 = __builtin_nontemporal_load((const f32x4*)(A + k0));
            f32x4 a1 = __builtin_nontemporal_load((const f32x4*)(A + k0 + 4));
            s16x8 v;
            v[0] = (short)f2b(a0.x); v[1] = (short)f2b(a0.y);
            v[2] = (short)f2b(a0.z); v[3] = (short)f2b(a0.w);
            v[4] = (short)f2b(a1.x); v[5] = (short)f2b(a1.y);
            v[6] = (short)f2b(a1.z); v[7] = (short)f2b(a1.w);
            afr[ks] = v;
        }
    }

    float drv[4];
#pragma unroll
    for (int q = 0; q < 4; ++q) drv[q] = dinv[r0 + kg * 4 + q];

    f32x4 acc[8];
#pragma unroll
    for (int ct = 0; ct < 8; ++ct) acc[ct] = (f32x4)(0.f);

    const ushort* Wls = (const ushort*)Wl;
#pragma unroll
    for (int ct = 0; ct < 8; ++ct) {
#pragma unroll
        for (int ks = 0; ks < 4; ++ks) {
            // lane-linear: frag f = ct*4+ks, byte addr = (f*64 + l)*16
            s16x8 bfr = *(const s16x8*)(Wls + ((ct * 4 + ks) * 64 + l) * 8);
            acc[ct] = __builtin_amdgcn_mfma_f32_16x16x32_bf16(
                          afr[ks], bfr, acc[ct], 0, 0, 0);
        }
    }

    // packed slab store: word w=l16 of (sl,row) = (col sl*32+l16, col +16)
#pragma unroll
    for (int sl = 0; sl < 4; ++sl) {
        uint* slab = H + (size_t)sl * N_NODES * 16 + (l & 15);
#pragma unroll
        for (int q = 0; q < 4; ++q) {
            int row = r0 + kg * 4 + q;
            uint wlo = f2b(acc[2 * sl][q] * drv[q]);
            uint whi = f2b(acc[2 * sl + 1][q] * drv[q]);
            slab[(size_t)row * 16] = wlo | (whi << 16);
        }
    }
}

// ----------------------------------- aggregate + LayerNorm + GELU (fused) ---
// Block = 4 nodes x 4 slices = 16 groups of 16 lanes (wave wv = slice wv).
// Group (sl, nl): gathers slice sl of node d = bid*4+nl (16 indices lane-
// parallel NT, double-buffered; 16 independent 64 B row gathers).
// Then: v = acc*dinv[d] + b; 16-lane reduce + LDS cross-slice reduce ->
// LN stats; y = LN(v)*g+be; o = gelu(y); LDS tile -> coalesced store.
// OUT_F32: out fp32 (final). else: z1 bf16 rows (layer-1 activation).
template<bool OUT_F32>
__global__ __launch_bounds__(256) void agg_ln_kernel(
        const uint* __restrict__ hs2, const float* __restrict__ dinv,
        const int* __restrict__ offsEnd, const int* __restrict__ srcPerm,
        const float* __restrict__ b, const float* __restrict__ g,
        const float* __restrict__ be,
        uint* __restrict__ z1, float* __restrict__ outf) {
    const int tid = threadIdx.x;
    const int l16 = tid & 15;
    const int grp = tid >> 4;          // 0..15
    const int sl  = grp >> 2;          // slice = wave id
    const int nl  = grp & 3;           // node within block
    const int gw16 = tid & 48;         // group base lane within wave
    const int d   = blockIdx.x * 4 + nl;   // 12500*4 == N exactly

    const uint* hcol = hs2 + (size_t)sl * N_NODES * 16 + l16;
    uint u = hcol[(size_t)d * 16];     // self-loop (pre-scaled)
    float acc0 = b2f((ushort)u);
    float acc1 = b2f((ushort)(u >> 16));

    const int beg = (d == 0) ? 0 : offsEnd[d - 1];
    const int end = offsEnd[d];

    int idx = (beg + l16 < end)
            ? __builtin_nontemporal_load(srcPerm + beg + l16) : 0;

    for (int base = beg; base < end; base += 16) {
        int m = end - base; if (m > 16) m = 16;
        int nbase = base + 16;
        int nidx = (nbase + l16 < end)
                 ? __builtin_nontemporal_load(srcPerm + nbase + l16) : 0;

        uint uu[16];
#pragma unroll
        for (int j = 0; j < 16; ++j) {
            int s = __shfl(idx, gw16 + j);   // 0 for j >= m (lane loaded 0)
            uu[j] = hcol[(size_t)s * 16];
        }
#pragma unroll
        for (int j = 0; j < 16; ++j) {
            uint val = (j < m) ? uu[j] : 0u;
            acc0 += b2f((ushort)val);
            acc1 += b2f((ushort)(val >> 16));
        }
        idx = nidx;
    }

    const float dd = dinv[d];
    const int col = sl * 32 + l16;
    float v0 = acc0 * dd + b[col];
    float v1 = acc1 * dd + b[col + 16];

    // LN stats: 16-lane group reduce, then cross-slice reduce via LDS
    float s  = v0 + v1;
    float s2 = v0 * v0 + v1 * v1;
#pragma unroll
    for (int off = 1; off < 16; off <<= 1) {
        s  += __shfl_xor(s,  off);
        s2 += __shfl_xor(s2, off);
    }
    __shared__ float2 st[4][4];        // [slice][node]
    __shared__ float  ot[4][HID];      // output tile (fp32; bf16 uses half)
    if (l16 == 0) st[sl][nl] = make_float2(s, s2);
    __syncthreads();
    float2 q0 = st[0][nl], q1 = st[1][nl], q2 = st[2][nl], q3 = st[3][nl];
    float S  = (q0.x + q1.x) + (q2.x + q3.x);
    float S2 = (q0.y + q1.y) + (q2.y + q3.y);
    float mu   = S  * (1.0f / 128.0f);
    float var  = S2 * (1.0f / 128.0f) - mu * mu;
    float rstd = rsqrtf(var + 1e-5f);
    float o0 = gelu_exact((v0 - mu) * rstd * g[col]      + be[col]);
    float o1 = gelu_exact((v1 - mu) * rstd * g[col + 16] + be[col + 16]);

    if (OUT_F32) {
        ot[nl][col] = o0; ot[nl][col + 16] = o1;
        __syncthreads();
        int node = tid >> 6, j = tid & 63;      // float2 per thread
        f32x2 w = *(const f32x2*)&ot[node][2 * j];
        __builtin_nontemporal_store(
            w, (f32x2*)&outf[((size_t)blockIdx.x * 4 + node) * HID + 2 * j]);
    } else {
        ushort* zt = (ushort*)ot;                // [4][128] bf16 tile
        zt[nl * HID + col] = f2b(o0);
        zt[nl * HID + col + 16] = f2b(o1);
        __syncthreads();
        int node = tid >> 6, j = tid & 63;      // u32 per thread
        uint w = *(const uint*)&zt[node * HID + 2 * j];
        z1[((size_t)blockIdx.x * 4 + node) * 64 + j] = w;
    }
}

// ---------------------------------------------------------------- launch ----
extern "C" void kernel_launch(void* const* d_in, const int* in_sizes, int n_in,
                              void* d_out, int out_size, void* d_ws, size_t ws_size,
                              hipStream_t stream) {
    const float* x   = (const float*)d_in[0];
    const int*   ei  = (const int*)d_in[1];   // [2, E] int32
    const float* W1  = (const float*)d_in[2];
    const float* b1  = (const float*)d_in[3];
    const float* W2  = (const float*)d_in[4];
    const float* b2  = (const float*)d_in[5];
    const float* g1  = (const float*)d_in[6];
    const float* be1 = (const float*)d_in[7];
    const float* g2  = (const float*)d_in[8];
    const float* be2 = (const float*)d_in[9];
    float* out = (float*)d_out;

    const int* src = ei;
    const int* dst = ei + N_EDGES;

    // ws: hs slab bf16 [4][N][32] | z1 bf16 [N][128] | srcPerm [E]
    //     | dinv [N] | offs [N] | cnt [N+pad] | bsum [256] | wfrag [2][8192]
    ushort* hs      = (ushort*)d_ws;
    ushort* z1      = hs + (size_t)N_NODES * HID;
    int*    srcPerm = (int*)(z1 + (size_t)N_NODES * HID);
    float*  dinv    = (float*)(srcPerm + N_EDGES);
    int*    offs    = (int*)(dinv + N_NODES);
    int*    cnt     = offs + N_NODES;
    int*    bsum    = cnt + 50016;               // cnt padded to /16
    uint*   wfrag   = (uint*)(bsum + 256);

    const int B = 256;
    const int nodeB = (N_NODES + B - 1) / B;            // 196
    const int e4    = N_EDGES / 4;                      // 150000 (exact)
    const int edge4B = (e4 + B - 1) / B;
    const int gemm_blocks = (N_NODES + 63) / 64;        // 782
    const int agg_blocks  = N_NODES / 4;                // 12500 (exact)
    const int zero4 = 50016 / 4;
    const int prepB = (16384 + zero4 + B - 1) / B;      // 113

    // prep (wfrag swizzle + cnt zero) + degree/CSR build
    prep_kernel<<<prepB, B, 0, stream>>>(W1, W2, wfrag, (u32x4*)cnt, zero4);
    count_deg_kernel<<<edge4B, B, 0, stream>>>((const int4*)dst, cnt, e4);
    reduce_dinv_kernel<<<nodeB, B, 0, stream>>>(cnt, dinv, bsum, N_NODES);
    scan_bsum_kernel<<<1, B, 0, stream>>>(bsum, nodeB);
    scan_block_kernel<<<nodeB, B, 0, stream>>>(cnt, bsum, offs, N_NODES);
    fill_csr_kernel<<<edge4B, B, 0, stream>>>((const int4*)src, (const int4*)dst,
                                              offs, srcPerm, e4);
    // post-fill: offs[d] == end of segment d

    // ---- layer 1: gemm (fp32 x) -> hs slab; agg+LN+GELU -> z1 bf16 ----
    gemm_mfma_kernel<false><<<gemm_blocks, B, 0, stream>>>(
        x, wfrag, dinv, (uint*)hs, N_NODES);
    agg_ln_kernel<false><<<agg_blocks, B, 0, stream>>>(
        (const uint*)hs, dinv, offs, srcPerm, b1, g1, be1,
        (uint*)z1, nullptr);

    // ---- layer 2: gemm (bf16 z1) -> hs slab; agg+LN+GELU -> out fp32 ----
    gemm_mfma_kernel<true><<<gemm_blocks, B, 0, stream>>>(
        z1, wfrag + 8192, dinv, (uint*)hs, N_NODES);
    agg_ln_kernel<true><<<agg_blocks, B, 0, stream>>>(
        (const uint*)hs, dinv, offs, srcPerm, b2, g2, be2,
        nullptr, out);
}